// Round 3
// baseline (799.616 us; speedup 1.0000x reference)
//
#include <hip/hip_runtime.h>

#define DD 64   // embedding dim, fixed by the problem

static inline size_t align16(size_t x) { return (x + 15) & ~(size_t)15; }

// ---------------- combined CSR build (social rows [0,U), inter rows [U,2U)) ----------------

__global__ __launch_bounds__(256) void hist2(
    const int* __restrict__ srows, const int* __restrict__ irows,
    int* __restrict__ counts, int ES, int EI, int U)
{
    int e = blockIdx.x * 256 + threadIdx.x;
    if (e < ES) atomicAdd(&counts[srows[e]], 1);
    else if (e < ES + EI) atomicAdd(&counts[U + irows[e - ES]], 1);
}

// Block scans 2048 elements (256 threads x 8). Exclusive scan out, block sum to bsums.
__global__ __launch_bounds__(256) void scan_partial(
    const int* __restrict__ in, int* __restrict__ out, int* __restrict__ bsums, int n)
{
    __shared__ int sh[256];
    int base = blockIdx.x * 2048 + threadIdx.x * 8;
    int v[8];
    int tsum = 0;
    #pragma unroll
    for (int j = 0; j < 8; ++j) {
        int idx = base + j;
        int x = (idx < n) ? in[idx] : 0;
        v[j] = tsum;
        tsum += x;
    }
    sh[threadIdx.x] = tsum;
    __syncthreads();
    for (int off = 1; off < 256; off <<= 1) {
        int t = (threadIdx.x >= off) ? sh[threadIdx.x - off] : 0;
        __syncthreads();
        sh[threadIdx.x] += t;
        __syncthreads();
    }
    int texc = sh[threadIdx.x] - tsum;
    #pragma unroll
    for (int j = 0; j < 8; ++j) {
        int idx = base + j;
        if (idx < n) out[idx] = texc + v[j];
    }
    if (threadIdx.x == 255) bsums[blockIdx.x] = sh[255];
}

__global__ void scan_top(int* bsums, int nb, int* row_ptr, int n)
{
    int run = 0;
    for (int i = 0; i < nb; ++i) { int t = bsums[i]; bsums[i] = run; run += t; }
    row_ptr[n] = run;
}

// adds block offsets and also initializes the scatter cursor
__global__ __launch_bounds__(256) void scan_add2(
    int* __restrict__ out, int* __restrict__ cursor, const int* __restrict__ bsums, int n)
{
    int i = blockIdx.x * 256 + threadIdx.x;
    if (i < n) { int v = out[i] + bsums[i >> 11]; out[i] = v; cursor[i] = v; }
}

// packs (col, val) into one 8B slot
__global__ __launch_bounds__(256) void scatter2(
    const int* __restrict__ srows, const int* __restrict__ scols, const float* __restrict__ svals,
    const int* __restrict__ irows, const int* __restrict__ icols, const float* __restrict__ ivals,
    int* __restrict__ cursor, uint2* __restrict__ edges, int ES, int EI, int U)
{
    int e = blockIdx.x * 256 + threadIdx.x;
    int row; uint2 ev;
    if (e < ES) {
        row = srows[e];
        ev.x = (unsigned)scols[e]; ev.y = __float_as_uint(svals[e]);
    } else if (e < ES + EI) {
        int i = e - ES;
        row = U + irows[i];
        ev.x = (unsigned)icols[i]; ev.y = __float_as_uint(ivals[i]);
    } else return;
    int slot = atomicAdd(&cursor[row], 1);
    edges[slot] = ev;
}

// ---------------- fused layer: spmm(social) -> concat -> GEMM [-> += spmm(inter)] ----------------
// Block = 256 threads, 64 rows. LDS: sIn[64][128] (concat input), sWt = W^T XOR-swizzled.
// GEMM tile per thread: 8 rows x 2 cols (lane lq=l&31 owns cols 2lq,2lq+1; half h=l>>5 owns 8-row half).
template<bool FUSE_INTER>
__global__ __launch_bounds__(256) void fused_layer(
    const float* __restrict__ uprev,   // [U,64]
    const float* __restrict__ item,    // item_emb (FUSE_INTER only)
    const int* __restrict__ row_ptr,   // combined [2U+1]
    const uint2* __restrict__ edges,   // combined (col,val)
    const float* __restrict__ w,       // [128,64] row-major
    float* __restrict__ out,           // [U,64]
    int U)
{
    __shared__ float sIn[64 * 128];
    __shared__ float sWt[64 * 128];
    const int t    = threadIdx.x;
    const int base = blockIdx.x * 64;

    // ---- stage W^T, XOR-swizzled: dw(col,j) = col*128 + ((((j>>2)^((col>>1)&7))<<2) | (j&3)) ----
    for (int i = t; i < 2048; i += 256) {
        int j  = i >> 4;            // W row 0..127
        int c4 = (i & 15) << 2;     // first of 4 cols
        float4 wv = reinterpret_cast<const float4*>(w)[i];
        float vv[4] = { wv.x, wv.y, wv.z, wv.w };
        #pragma unroll
        for (int e2 = 0; e2 < 4; ++e2) {
            int col = c4 + e2;
            int dw  = col * 128 + ((((j >> 2) ^ ((col >> 1) & 7)) << 2) | (j & 3));
            sWt[dw] = vv[e2];
        }
    }

    // ---- phase 1: social spmm gather, 16-lane group per row; concat [new_u | u] into sIn ----
    {
        const int g    = t >> 4;
        const int lane = t & 15;
        #pragma unroll
        for (int rr = 0; rr < 4; ++rr) {
            const int lr   = g + rr * 16;
            const int grow = base + lr;
            if (grow < U) {
                int s = row_ptr[grow], e = row_ptr[grow + 1];
                float4 acc = make_float4(0.f, 0.f, 0.f, 0.f);
                for (int i = s; i < e; ++i) {
                    uint2 ev = edges[i];
                    float v  = __uint_as_float(ev.y);
                    const float4 xv = *reinterpret_cast<const float4*>(
                        uprev + (size_t)ev.x * DD + lane * 4);
                    acc.x += v * xv.x; acc.y += v * xv.y;
                    acc.z += v * xv.z; acc.w += v * xv.w;
                }
                const float4 uv = *reinterpret_cast<const float4*>(
                    uprev + (size_t)grow * DD + lane * 4);
                *reinterpret_cast<float4*>(&sIn[lr * 128 + lane * 4])      = acc;
                *reinterpret_cast<float4*>(&sIn[lr * 128 + 64 + lane * 4]) = uv;
            }
        }
    }
    __syncthreads();

    // ---- phase 2: register-tiled GEMM ----
    const int w_ = t >> 6;          // wave 0..3 -> rows w_*16 .. +15
    const int l  = t & 63;
    const int h  = l >> 5;          // row half
    const int lq = l & 31;
    const int c0 = lq * 2;
    const int rb = w_ * 16 + h * 8;
    const int sw = lq & 7;          // == (c0>>1)&7 == ((c0+1)>>1)&7

    float acc[8][2];
    #pragma unroll
    for (int r = 0; r < 8; ++r) { acc[r][0] = 0.f; acc[r][1] = 0.f; }

    #pragma unroll 4
    for (int j4 = 0; j4 < 32; ++j4) {
        int so = ((j4 ^ sw) << 2);
        float4 w40 = *reinterpret_cast<const float4*>(&sWt[c0 * 128 + so]);
        float4 w41 = *reinterpret_cast<const float4*>(&sWt[(c0 + 1) * 128 + so]);
        #pragma unroll
        for (int r = 0; r < 8; ++r) {
            float4 iv = *reinterpret_cast<const float4*>(&sIn[(rb + r) * 128 + j4 * 4]);
            acc[r][0] += iv.x * w40.x + iv.y * w40.y + iv.z * w40.z + iv.w * w40.w;
            acc[r][1] += iv.x * w41.x + iv.y * w41.y + iv.z * w41.z + iv.w * w41.w;
        }
    }

    if (!FUSE_INTER) {
        #pragma unroll
        for (int r = 0; r < 8; ++r) {
            int grow = base + rb + r;
            if (grow < U)
                *reinterpret_cast<float2*>(&out[(size_t)grow * DD + c0]) =
                    make_float2(acc[r][0], acc[r][1]);
        }
    } else {
        // park GEMM result in sIn[lr][0..63] (each wave touches only its own rows)
        #pragma unroll
        for (int r = 0; r < 8; ++r)
            *reinterpret_cast<float2*>(&sIn[(rb + r) * 128 + c0]) =
                make_float2(acc[r][0], acc[r][1]);
        __syncthreads();
        // inter spmm gather-add, same 16-lane-group partition as phase 1
        const int g    = t >> 4;
        const int lane = t & 15;
        #pragma unroll
        for (int rr = 0; rr < 4; ++rr) {
            const int lr   = g + rr * 16;
            const int grow = base + lr;
            if (grow < U) {
                int s = row_ptr[U + grow], e = row_ptr[U + grow + 1];
                float4 a4 = *reinterpret_cast<const float4*>(&sIn[lr * 128 + lane * 4]);
                for (int i = s; i < e; ++i) {
                    uint2 ev = edges[i];
                    float v  = __uint_as_float(ev.y);
                    const float4 xv = *reinterpret_cast<const float4*>(
                        item + (size_t)ev.x * DD + lane * 4);
                    a4.x += v * xv.x; a4.y += v * xv.y;
                    a4.z += v * xv.z; a4.w += v * xv.w;
                }
                *reinterpret_cast<float4*>(&out[(size_t)grow * DD + lane * 4]) = a4;
            }
        }
    }
}

extern "C" void kernel_launch(void* const* d_in, const int* in_sizes, int n_in,
                              void* d_out, int out_size, void* d_ws, size_t ws_size,
                              hipStream_t stream)
{
    const float* user_emb    = (const float*)d_in[0];
    const float* item_emb    = (const float*)d_in[1];
    const float* weights     = (const float*)d_in[2];
    const float* social_vals = (const float*)d_in[3];
    const float* inter_vals  = (const float*)d_in[4];
    const int*   social_rows = (const int*)d_in[5];
    const int*   social_cols = (const int*)d_in[6];
    const int*   inter_rows  = (const int*)d_in[7];
    const int*   inter_cols  = (const int*)d_in[8];

    const int D  = DD;
    const int U  = in_sizes[0] / D;
    const int I  = in_sizes[1] / D;
    const int L  = in_sizes[2] / (2 * D * D);
    const int ES = in_sizes[3];
    const int EI = in_sizes[4];

    float* out      = (float*)d_out;           // final_u [U, D]
    float* out_item = out + (size_t)U * D;     // item_emb passthrough [I, D]

    // ---- workspace layout ----
    char* p = (char*)d_ws;
    size_t off = 0;
    auto take = [&](size_t bytes) { char* r = p + off; off += align16(bytes); return r; };

    const int n2 = 2 * U;
    int*   row_ptr = (int*)take((size_t)(n2 + 1) * sizeof(int));
    int*   counts  = (int*)take((size_t)n2 * sizeof(int));
    int*   cursor  = (int*)take((size_t)n2 * sizeof(int));
    int*   bsums   = (int*)take(1024 * sizeof(int));
    uint2* edges   = (uint2*)take((size_t)(ES + EI) * sizeof(uint2));
    float* uB      = (float*)take((size_t)U * D * sizeof(float));
    float* uC      = (float*)take((size_t)U * D * sizeof(float));

    // ---- combined CSR build ----
    const int Etot = ES + EI;
    hipMemsetAsync(counts, 0, (size_t)n2 * sizeof(int), stream);
    hist2<<<(Etot + 255) / 256, 256, 0, stream>>>(social_rows, inter_rows, counts, ES, EI, U);
    const int nb = (n2 + 2047) / 2048;
    scan_partial<<<nb, 256, 0, stream>>>(counts, row_ptr, bsums, n2);
    scan_top<<<1, 1, 0, stream>>>(bsums, nb, row_ptr, n2);
    scan_add2<<<(n2 + 255) / 256, 256, 0, stream>>>(row_ptr, cursor, bsums, n2);
    scatter2<<<(Etot + 255) / 256, 256, 0, stream>>>(
        social_rows, social_cols, social_vals,
        inter_rows, inter_cols, inter_vals,
        cursor, edges, ES, EI, U);

    // ---- layers ----
    const int grid = (U + 63) / 64;
    const float* uprev = user_emb;
    int which = 0;
    for (int k = 0; k < L; ++k) {
        const float* wk = weights + (size_t)k * 2 * D * D;
        if (k == L - 1) {
            fused_layer<true><<<grid, 256, 0, stream>>>(
                uprev, item_emb, row_ptr, edges, wk, out, U);
        } else {
            float* unext = which ? uC : uB;
            fused_layer<false><<<grid, 256, 0, stream>>>(
                uprev, nullptr, row_ptr, edges, wk, unext, U);
            uprev = unext;
            which ^= 1;
        }
    }

    // output 1: item_emb passthrough
    hipMemcpyAsync(out_item, item_emb, (size_t)I * D * sizeof(float),
                   hipMemcpyDeviceToDevice, stream);
}

// Round 4
// 542.998 us; speedup vs baseline: 1.4726x; 1.4726x over previous
//
#include <hip/hip_runtime.h>

#define DD 64   // embedding dim, fixed by the problem

static inline size_t align16(size_t x) { return (x + 15) & ~(size_t)15; }

__device__ __forceinline__ unsigned bf16rn(float f) {
    unsigned u = __float_as_uint(f);
    return (u + 0x7fffu + ((u >> 16) & 1u)) >> 16;   // RNE, NaN not expected here
}

// ---------------- combined CSR build (social rows [0,U), inter rows [U,2U)) ----------------

__global__ __launch_bounds__(256) void hist2(
    const int* __restrict__ srows, const int* __restrict__ irows,
    int* __restrict__ counts, int ES, int EI, int U)
{
    int e = blockIdx.x * 256 + threadIdx.x;
    if (e < ES) atomicAdd(&counts[srows[e]], 1);
    else if (e < ES + EI) atomicAdd(&counts[U + irows[e - ES]], 1);
}

__global__ __launch_bounds__(256) void scan_partial(
    const int* __restrict__ in, int* __restrict__ out, int* __restrict__ bsums, int n)
{
    __shared__ int sh[256];
    int base = blockIdx.x * 2048 + threadIdx.x * 8;
    int v[8];
    int tsum = 0;
    #pragma unroll
    for (int j = 0; j < 8; ++j) {
        int idx = base + j;
        int x = (idx < n) ? in[idx] : 0;
        v[j] = tsum;
        tsum += x;
    }
    sh[threadIdx.x] = tsum;
    __syncthreads();
    for (int off = 1; off < 256; off <<= 1) {
        int t = (threadIdx.x >= off) ? sh[threadIdx.x - off] : 0;
        __syncthreads();
        sh[threadIdx.x] += t;
        __syncthreads();
    }
    int texc = sh[threadIdx.x] - tsum;
    #pragma unroll
    for (int j = 0; j < 8; ++j) {
        int idx = base + j;
        if (idx < n) out[idx] = texc + v[j];
    }
    if (threadIdx.x == 255) bsums[blockIdx.x] = sh[255];
}

__global__ void scan_top(int* bsums, int nb, int* row_ptr, int n)
{
    int run = 0;
    for (int i = 0; i < nb; ++i) { int t = bsums[i]; bsums[i] = run; run += t; }
    row_ptr[n] = run;
}

__global__ __launch_bounds__(256) void scan_add2(
    int* __restrict__ out, int* __restrict__ cursor, const int* __restrict__ bsums, int n)
{
    int i = blockIdx.x * 256 + threadIdx.x;
    if (i < n) { int v = out[i] + bsums[i >> 11]; out[i] = v; cursor[i] = v; }
}

__global__ __launch_bounds__(256) void scatter2(
    const int* __restrict__ srows, const int* __restrict__ scols, const float* __restrict__ svals,
    const int* __restrict__ irows, const int* __restrict__ icols, const float* __restrict__ ivals,
    int* __restrict__ cursor, uint2* __restrict__ edges, int ES, int EI, int U)
{
    int e = blockIdx.x * 256 + threadIdx.x;
    int row; uint2 ev;
    if (e < ES) {
        row = srows[e];
        ev.x = (unsigned)scols[e]; ev.y = __float_as_uint(svals[e]);
    } else if (e < ES + EI) {
        int i = e - ES;
        row = U + irows[i];
        ev.x = (unsigned)icols[i]; ev.y = __float_as_uint(ivals[i]);
    } else return;
    int slot = atomicAdd(&cursor[row], 1);
    edges[slot] = ev;
}

// ---------------- fp32 -> bf16 table conversion ----------------
__global__ __launch_bounds__(256) void f32_to_bf16_k(
    const float* __restrict__ in, ushort* __restrict__ out, int n8)
{
    int i = blockIdx.x * 256 + threadIdx.x;
    if (i >= n8) return;
    const float4* p = reinterpret_cast<const float4*>(in) + (size_t)i * 2;
    float4 A = p[0], B = p[1];
    uint4 r;
    r.x = bf16rn(A.x) | (bf16rn(A.y) << 16);
    r.y = bf16rn(A.z) | (bf16rn(A.w) << 16);
    r.z = bf16rn(B.x) | (bf16rn(B.y) << 16);
    r.w = bf16rn(B.z) | (bf16rn(B.w) << 16);
    reinterpret_cast<uint4*>(out)[i] = r;
}

// ---------------- SpMM (CSR row-gather, bf16 source, fp32 accumulate) ----------------
// 16 lanes per destination row; each lane owns 4 of the 64 columns (8B bf16 gather/lane).
template <bool ADD>
__global__ __launch_bounds__(256) void spmm_bf16(
    const int* __restrict__ row_ptr, const uint2* __restrict__ edges,
    const ushort* __restrict__ xb,   // bf16 [nx,64]
    float* __restrict__ out, int nrows)
{
    int g    = (blockIdx.x * 256 + threadIdx.x) >> 4;
    int lane = threadIdx.x & 15;
    if (g >= nrows) return;
    int s = row_ptr[g], e = row_ptr[g + 1];
    float4 acc = make_float4(0.f, 0.f, 0.f, 0.f);
    int i = s;
    for (; i + 1 < e; i += 2) {
        uint2 e0 = edges[i], e1 = edges[i + 1];
        uint2 x0 = *reinterpret_cast<const uint2*>(xb + ((size_t)e0.x << 6) + lane * 4);
        uint2 x1 = *reinterpret_cast<const uint2*>(xb + ((size_t)e1.x << 6) + lane * 4);
        float v0 = __uint_as_float(e0.y);
        float v1 = __uint_as_float(e1.y);
        acc.x += v0 * __uint_as_float(x0.x << 16);
        acc.y += v0 * __uint_as_float(x0.x & 0xffff0000u);
        acc.z += v0 * __uint_as_float(x0.y << 16);
        acc.w += v0 * __uint_as_float(x0.y & 0xffff0000u);
        acc.x += v1 * __uint_as_float(x1.x << 16);
        acc.y += v1 * __uint_as_float(x1.x & 0xffff0000u);
        acc.z += v1 * __uint_as_float(x1.y << 16);
        acc.w += v1 * __uint_as_float(x1.y & 0xffff0000u);
    }
    if (i < e) {
        uint2 e0 = edges[i];
        uint2 x0 = *reinterpret_cast<const uint2*>(xb + ((size_t)e0.x << 6) + lane * 4);
        float v0 = __uint_as_float(e0.y);
        acc.x += v0 * __uint_as_float(x0.x << 16);
        acc.y += v0 * __uint_as_float(x0.x & 0xffff0000u);
        acc.z += v0 * __uint_as_float(x0.y << 16);
        acc.w += v0 * __uint_as_float(x0.y & 0xffff0000u);
    }
    float* o = out + ((size_t)g << 6) + lane * 4;
    if (ADD) {
        float4 cur = *reinterpret_cast<const float4*>(o);
        acc.x += cur.x; acc.y += cur.y; acc.z += cur.z; acc.w += cur.w;
    }
    *reinterpret_cast<float4*>(o) = acc;
}

// ---------------- register-tiled concat GEMM ----------------
// Block = 256 threads, 64 rows. sIn[64][128] = [a|b] rows; sWt = W^T XOR-swizzled.
// Thread tile: 8 rows x 2 cols. Optionally emits a bf16 copy of the output.
__global__ __launch_bounds__(256) void gemm2(
    const float* __restrict__ a,     // new_u (spmm result) [U,64]
    const float* __restrict__ b,     // u (prev embedding)  [U,64]
    const float* __restrict__ w,     // [128,64] row-major
    float* __restrict__ outf,        // fp32 out [U,64] (may alias b - block-local rows only)
    ushort* __restrict__ outb,       // bf16 out [U,64] or nullptr
    int U)
{
    __shared__ float sIn[64 * 128];
    __shared__ float sWt[64 * 128];
    const int t    = threadIdx.x;
    const int base = blockIdx.x * 64;

    // stage W^T, XOR-swizzled: dw(col,j) = col*128 + ((((j>>2)^((col>>1)&7))<<2) | (j&3))
    for (int i = t; i < 2048; i += 256) {
        int j  = i >> 4;
        int c4 = (i & 15) << 2;
        float4 wv = reinterpret_cast<const float4*>(w)[i];
        float vv[4] = { wv.x, wv.y, wv.z, wv.w };
        #pragma unroll
        for (int e2 = 0; e2 < 4; ++e2) {
            int col = c4 + e2;
            int dw  = col * 128 + ((((j >> 2) ^ ((col >> 1) & 7)) << 2) | (j & 3));
            sWt[dw] = vv[e2];
        }
    }
    // stage inputs: sIn[row][0..63] = a-row, [64..127] = b-row
    for (int i = t; i < 2048; i += 256) {
        int row  = i >> 5;
        int q    = i & 31;
        int grow = base + row;
        float4 v = make_float4(0.f, 0.f, 0.f, 0.f);
        int qq = q & 15;
        if (grow < U) {
            const float* src = (q < 16) ? a : b;
            v = *reinterpret_cast<const float4*>(src + ((size_t)grow << 6) + qq * 4);
        }
        int off = (q < 16) ? qq * 4 : 64 + qq * 4;
        *reinterpret_cast<float4*>(&sIn[row * 128 + off]) = v;
    }
    __syncthreads();

    // register-tiled GEMM
    const int w_ = t >> 6;
    const int l  = t & 63;
    const int h  = l >> 5;
    const int lq = l & 31;
    const int c0 = lq * 2;
    const int rb = w_ * 16 + h * 8;
    const int sw = lq & 7;

    float acc[8][2];
    #pragma unroll
    for (int r = 0; r < 8; ++r) { acc[r][0] = 0.f; acc[r][1] = 0.f; }

    #pragma unroll 4
    for (int j4 = 0; j4 < 32; ++j4) {
        int so = ((j4 ^ sw) << 2);
        float4 w40 = *reinterpret_cast<const float4*>(&sWt[c0 * 128 + so]);
        float4 w41 = *reinterpret_cast<const float4*>(&sWt[(c0 + 1) * 128 + so]);
        #pragma unroll
        for (int r = 0; r < 8; ++r) {
            float4 iv = *reinterpret_cast<const float4*>(&sIn[(rb + r) * 128 + j4 * 4]);
            acc[r][0] += iv.x * w40.x + iv.y * w40.y + iv.z * w40.z + iv.w * w40.w;
            acc[r][1] += iv.x * w41.x + iv.y * w41.y + iv.z * w41.z + iv.w * w41.w;
        }
    }

    #pragma unroll
    for (int r = 0; r < 8; ++r) {
        int grow = base + rb + r;
        if (grow < U) {
            *reinterpret_cast<float2*>(&outf[((size_t)grow << 6) + c0]) =
                make_float2(acc[r][0], acc[r][1]);
            if (outb) {
                unsigned pk = bf16rn(acc[r][0]) | (bf16rn(acc[r][1]) << 16);
                *reinterpret_cast<unsigned*>(outb + ((size_t)grow << 6) + c0) = pk;
            }
        }
    }
}

extern "C" void kernel_launch(void* const* d_in, const int* in_sizes, int n_in,
                              void* d_out, int out_size, void* d_ws, size_t ws_size,
                              hipStream_t stream)
{
    const float* user_emb    = (const float*)d_in[0];
    const float* item_emb    = (const float*)d_in[1];
    const float* weights     = (const float*)d_in[2];
    const float* social_vals = (const float*)d_in[3];
    const float* inter_vals  = (const float*)d_in[4];
    const int*   social_rows = (const int*)d_in[5];
    const int*   social_cols = (const int*)d_in[6];
    const int*   inter_rows  = (const int*)d_in[7];
    const int*   inter_cols  = (const int*)d_in[8];

    const int D  = DD;
    const int U  = in_sizes[0] / D;
    const int I  = in_sizes[1] / D;
    const int L  = in_sizes[2] / (2 * D * D);
    const int ES = in_sizes[3];
    const int EI = in_sizes[4];

    float* out      = (float*)d_out;           // final_u [U, D]
    float* out_item = out + (size_t)U * D;     // item_emb passthrough [I, D]

    // ---- workspace layout ----
    char* p = (char*)d_ws;
    size_t off = 0;
    auto take = [&](size_t bytes) { char* r = p + off; off += align16(bytes); return r; };

    const int n2 = 2 * U;
    int*    row_ptr = (int*)take((size_t)(n2 + 1) * sizeof(int));
    int*    counts  = (int*)take((size_t)n2 * sizeof(int));
    int*    cursor  = (int*)take((size_t)n2 * sizeof(int));
    int*    bsums   = (int*)take(1024 * sizeof(int));
    uint2*  edges   = (uint2*)take((size_t)(ES + EI) * sizeof(uint2));
    ushort* ubf     = (ushort*)take((size_t)U * D * sizeof(ushort));  // bf16 gather table (users)
    ushort* ibf     = (ushort*)take((size_t)I * D * sizeof(ushort));  // bf16 gather table (items)
    float*  tmpA    = (float*)take((size_t)U * D * sizeof(float));    // spmm result
    float*  uB      = (float*)take((size_t)U * D * sizeof(float));    // fp32 u (layers >= 1)

    // ---- combined CSR build ----
    const int Etot = ES + EI;
    hipMemsetAsync(counts, 0, (size_t)n2 * sizeof(int), stream);
    hist2<<<(Etot + 255) / 256, 256, 0, stream>>>(social_rows, inter_rows, counts, ES, EI, U);
    const int nb = (n2 + 2047) / 2048;
    scan_partial<<<nb, 256, 0, stream>>>(counts, row_ptr, bsums, n2);
    scan_top<<<1, 1, 0, stream>>>(bsums, nb, row_ptr, n2);
    scan_add2<<<(n2 + 255) / 256, 256, 0, stream>>>(row_ptr, cursor, bsums, n2);
    scatter2<<<(Etot + 255) / 256, 256, 0, stream>>>(
        social_rows, social_cols, social_vals,
        inter_rows, inter_cols, inter_vals,
        cursor, edges, ES, EI, U);

    // ---- bf16 gather tables ----
    const int u8 = U * D / 8, i8 = I * D / 8;
    f32_to_bf16_k<<<(u8 + 255) / 256, 256, 0, stream>>>(user_emb, ubf, u8);
    f32_to_bf16_k<<<(i8 + 255) / 256, 256, 0, stream>>>(item_emb, ibf, i8);

    // ---- layers ----
    const int spmm_grid = ((U * 16) + 255) / 256;
    const int gemm_grid = (U + 63) / 64;
    const float* uprev = user_emb;
    for (int k = 0; k < L; ++k) {
        const float* wk = weights + (size_t)k * 2 * D * D;
        spmm_bf16<false><<<spmm_grid, 256, 0, stream>>>(row_ptr, edges, ubf, tmpA, U);
        if (k == L - 1) {
            gemm2<<<gemm_grid, 256, 0, stream>>>(tmpA, uprev, wk, out, (ushort*)nullptr, U);
        } else {
            // writes fp32 into uB (in-place safe: block stages its rows before writing)
            // and refreshes the bf16 gather table for the next layer's spmm
            gemm2<<<gemm_grid, 256, 0, stream>>>(tmpA, uprev, wk, uB, ubf, U);
            uprev = uB;
        }
    }

    // final_u += A_inter @ item_emb (bf16 gather, fp32 accumulate into d_out)
    spmm_bf16<true><<<spmm_grid, 256, 0, stream>>>(row_ptr + U, edges, ibf, out, U);

    // output 1: item_emb passthrough
    hipMemcpyAsync(out_item, item_emb, (size_t)I * D * sizeof(float),
                   hipMemcpyDeviceToDevice, stream);
}